// Round 4
// baseline (95.663 us; speedup 1.0000x reference)
//
#include <hip/hip_runtime.h>
#include <math.h>

#define G      7
#define NCELL  49
#define NBOX   98
#define CH     30
#define RAWF   1470
#define BATCH  8192
#define NB     2      // batches per wave, software-pipelined

// Wave-internal LDS visibility: drain this wave's outstanding DS ops.
#define WAVE_SYNC() asm volatile("s_waitcnt lgkmcnt(0)" ::: "memory")

__device__ __forceinline__ float sigmoidf_(float x) {
    return 1.0f / (1.0f + expf(-x));
}
// Broadcast lane i's value to all lanes (i wave-uniform SGPR). Pure VALU.
__device__ __forceinline__ float rdlanef(float x, int i) {
    return __int_as_float(__builtin_amdgcn_readlane(__float_as_int(x), i));
}
// Correctly-rounded x/7 (Markstein 2-fma refinement == IEEE x/7.0f here).
__device__ __forceinline__ float div7(float x) {
    const float r7 = 1.0f / 7.0f;
    float q0 = x * r7;
    float e  = fmaf(-7.0f, q0, x);
    return fmaf(e, r7, q0);
}

// Fallback (unreachable with active-filtering; kept for safety) V in (64,98].
__device__ __forceinline__ void nms_slow(const float4* sbox, const float2* smeta,
                                         int V, int lane, float4 mb, float2 mm,
                                         float mlab, unsigned long long& k0,
                                         unsigned long long& k1) {
    const double UD = (double)0.3f + 0x1p-26;
    const int i2c = (lane + 64 < NBOX) ? lane + 64 : NBOX - 1;
    const float4 mb2 = sbox[i2c];
    const float2 mm2 = smeta[i2c];
    const float mlab2 = (lane + 64 < V) ? mm2.y : -1.0f;
    for (int i = 0; i < V; ++i) {
        float bx, by, bz, bw, ba, bl;
        if (i < 64) {
            bx = rdlanef(mb.x, i);  by = rdlanef(mb.y, i);
            bz = rdlanef(mb.z, i);  bw = rdlanef(mb.w, i);
            ba = rdlanef(mm.x, i);  bl = rdlanef(mlab, i);
        } else {
            bx = rdlanef(mb2.x, i - 64);  by = rdlanef(mb2.y, i - 64);
            bz = rdlanef(mb2.z, i - 64);  bw = rdlanef(mb2.w, i - 64);
            ba = rdlanef(mm2.x, i - 64);  bl = rdlanef(mlab2, i - 64);
        }
        float w1 = fmaxf(fminf(bz, mb.z) - fmaxf(bx, mb.x), 0.0f);
        float h1 = fmaxf(fminf(bw, mb.w) - fmaxf(by, mb.y), 0.0f);
        float i1 = w1 * h1;
        float u1 = fmaxf(ba + mm.x - i1, 1e-9f);
        bool hit1 = ((double)i1 > UD * (double)u1) && (bl == mlab);
        float w2 = fmaxf(fminf(bz, mb2.z) - fmaxf(bx, mb2.x), 0.0f);
        float h2 = fmaxf(fminf(bw, mb2.w) - fmaxf(by, mb2.y), 0.0f);
        float i2 = w2 * h2;
        float u2 = fmaxf(ba + mm2.x - i2, 1e-9f);
        bool hit2 = ((double)i2 > UD * (double)u2) && (bl == mlab2);
        unsigned long long row0 = __ballot(hit1);
        unsigned long long row1 = __ballot(hit2);
        if (((row0 & k0) | (row1 & k1)) == 0ull) {
            if (i < 64) k0 |= 1ull << i;
            else        k1 |= 1ull << (i - 64);
        }
    }
}

__global__ __launch_bounds__(128, 4) void yolo_nms_kernel(
    const float* __restrict__ p,
    float* __restrict__ out_boxes,   // [B,98,4]
    float* __restrict__ out_scores,  // [B,98]
    float* __restrict__ out_labels,  // [B,98]
    float* __restrict__ out_keep)    // [B,98]
{
#pragma clang fp contract(off)
    // Per-wave LDS, reused across NB iterations (DS ops are in-order per wave,
    // so iteration i+1's writes can't pass iteration i's NMS reads).
    __shared__ __align__(16) float4 sboxS[2][NBOX];   // 3136 B
    __shared__ __align__(8)  float2 smetaS[2][NBOX];  // 1568 B (area, label)

    const int lane = threadIdx.x & 63;
    const int wv   = threadIdx.x >> 6;
    const int wave = blockIdx.x * 2 + wv;     // 0..4095; wave owns NB batches
    const int b0   = wave * NB;

    float4* sbox  = sboxS[wv];
    float2* smeta = smetaS[wv];

    // ---- prefetch batch b0's row: 15 independent float2 loads ----
    float2 cur[15], nxt[15];
    if (lane < NCELL) {
        const float2* q2 = (const float2*)(p + (size_t)b0 * RAWF + lane * CH);
        #pragma unroll
        for (int k = 0; k < 15; ++k) cur[k] = q2[k];
    }

    #pragma unroll
    for (int it = 0; it < NB; ++it) {
        const int b = b0 + it;

        // ---- issue next batch's loads NOW; latency hides under this batch ----
        if (it + 1 < NB && lane < NCELL) {
            const float2* qn = (const float2*)(p + (size_t)(b + 1) * RAWF + lane * CH);
            #pragma unroll
            for (int k = 0; k < 15; ++k) nxt[k] = qn[k];
        }

        // ---- lane-per-cell decode: lane L < 49 owns cell L = boxes {2L,2L+1} ----
        float4 bb0 = make_float4(0.f, 0.f, 0.f, 0.f);
        float4 bb1 = make_float4(0.f, 0.f, 0.f, 0.f);
        float s0 = -1.0f, s1 = -1.0f, area0 = 0.0f, area1 = 0.0f, lab = 0.0f;
        bool vld0 = false, vld1 = false, act0 = false, act1 = false;

        if (lane < NCELL) {
            float2 xy0 = cur[0];   // tx0, ty0
            float2 wh0 = cur[1];   // tw0, th0
            float2 xy1 = cur[2];   // tx1, ty1
            float2 wh1 = cur[3];   // tw1, th1
            float2 cf  = cur[4];   // conf0, conf1
            // class argmax, two independent chains (x-side even idx, y-side odd),
            // first-max merge == jnp.argmax semantics.
            float2 c0 = cur[5];
            float bx = c0.x; int ix = 0;
            float by = c0.y; int iy = 1;
            #pragma unroll
            for (int k2 = 1; k2 < 10; ++k2) {
                float2 cv = cur[5 + k2];
                if (cv.x > bx) { bx = cv.x; ix = 2 * k2; }
                if (cv.y > by) { by = cv.y; iy = 2 * k2 + 1; }
            }
            const int bi = (by > bx) ? iy : ix;  // tie: iy>ix, keep ix (first)
            lab = (float)(bi + 1);

            const int r = lane / G, c = lane - r * G;
            float gx0 = div7(sigmoidf_(xy0.x) + (float)c);
            float gy0 = div7(sigmoidf_(xy0.y) + (float)r);
            float gx1 = div7(sigmoidf_(xy1.x) + (float)c);
            float gy1 = div7(sigmoidf_(xy1.y) + (float)r);
            float hx0 = wh0.x * 0.5f, hy0 = wh0.y * 0.5f;
            float hx1 = wh1.x * 0.5f, hy1 = wh1.y * 0.5f;
            bb0 = make_float4(gx0 - hx0, gy0 - hy0, gx0 + hx0, gy0 + hy0);
            bb1 = make_float4(gx1 - hx1, gy1 - hy1, gx1 + hx1, gy1 + hy1);
            area0 = fmaxf(bb0.z - bb0.x, 0.0f) * fmaxf(bb0.w - bb0.y, 0.0f);
            area1 = fmaxf(bb1.z - bb1.x, 0.0f) * fmaxf(bb1.w - bb1.y, 0.0f);
            s0 = sigmoidf_(cf.x);
            s1 = sigmoidf_(cf.y);
            vld0 = (s0 > 0.5f);
            vld1 = (s1 > 0.5f);
            // Zero-area boxes are provably inert under reference NMS (inter==0
            // bitwise for every partner): keep = valid, never suppress. Only
            // active boxes enter sort + NMS.
            act0 = vld0 && (area0 > 0.0f);
            act1 = vld1 && (area1 > 0.0f);

            float4* ob = (float4*)(out_boxes + (size_t)b * (NBOX * 4));
            ob[2 * lane]     = bb0;
            ob[2 * lane + 1] = bb1;
            ((float2*)(out_scores + (size_t)b * NBOX))[lane] = make_float2(s0, s1);
            ((float2*)(out_labels + (size_t)b * NBOX))[lane] = make_float2(lab, lab);
        }

        // ---- active masks (bits confined to lanes 0..48) ----
        unsigned long long m0 = __ballot(act0);   // even boxes 2L
        unsigned long long m1 = __ballot(act1);   // odd boxes 2L+1
        const int V = __popcll(m0) + __popcll(m1);   // E[V] ~ 12

        // ---- stable descending rank via ballot-mask walk + readlane (no LDS).
        // rank = #{active j : s_j > s_me or (s_j == s_me and orig_j < orig_me)}.
        int rk0 = 0, rk1 = 0;
        unsigned long long t0 = m0;
        while (t0) {
            int jl = __builtin_ctzll(t0); t0 &= t0 - 1ull;
            float sj = rdlanef(s0, jl);
            rk0 += (sj > s0) || ((sj == s0) && (jl <  lane));   // 2jl < 2L
            rk1 += (sj > s1) || ((sj == s1) && (jl <= lane));   // 2jl < 2L+1
        }
        unsigned long long t1 = m1;
        while (t1) {
            int jl = __builtin_ctzll(t1); t1 &= t1 - 1ull;
            float sj = rdlanef(s1, jl);
            rk0 += (sj > s0) || ((sj == s0) && (jl < lane));    // 2jl+1 < 2L
            rk1 += (sj > s1) || ((sj == s1) && (jl < lane));    // 2jl+1 < 2L+1
        }

        // ---- push active boxes to rank-sorted slots; lane <- rank ----
        if (act0) { sbox[rk0] = bb0; smeta[rk0] = make_float2(area0, lab); }
        if (act1) { sbox[rk1] = bb1; smeta[rk1] = make_float2(area1, lab); }
        WAVE_SYNC();
        const float4 mb = sbox[lane];
        const float2 mm = smeta[lane];
        const float mlab = (lane < V) ? mm.y : -1.0f;  // sentinel kills garbage

        // ---- fused NMS over active boxes (~12 rows) ----
        unsigned long long k0 = 0ull, k1 = 0ull;
        // exact predicate: RN(inter/uc) > 0.3f <=> inter > (0.3f+2^-26)*uc (f64 exact)
        const double UD = (double)0.3f + 0x1p-26;

#define ROW_HIT_LDS(BI, MI, HIT) do {                                    \
        float w = fmaxf(fminf((BI).z, mb.z) - fmaxf((BI).x, mb.x), 0.0f);\
        float h = fmaxf(fminf((BI).w, mb.w) - fmaxf((BI).y, mb.y), 0.0f);\
        float inter = w * h;                                             \
        float uc = fmaxf((MI).x + mm.x - inter, 1e-9f);                  \
        HIT = ((double)inter > UD * (double)uc) && ((MI).y == mlab);     \
    } while (0)

        if (V <= 64) {
            int i = 0;
            for (; i + 4 <= V; i += 4) {   // 4 independent row chains in flight
                float4 bA = sbox[i],     bB = sbox[i + 1];
                float4 bC = sbox[i + 2], bD = sbox[i + 3];
                float2 mA = smeta[i],     mB = smeta[i + 1];
                float2 mC = smeta[i + 2], mD = smeta[i + 3];
                bool hA, hB, hC, hD;
                ROW_HIT_LDS(bA, mA, hA);
                ROW_HIT_LDS(bB, mB, hB);
                ROW_HIT_LDS(bC, mC, hC);
                ROW_HIT_LDS(bD, mD, hD);
                unsigned long long rA = __ballot(hA);
                unsigned long long rB = __ballot(hB);
                unsigned long long rC = __ballot(hC);
                unsigned long long rD = __ballot(hD);
                k0 |= ((rA & k0) == 0ull) ? (1ull << i) : 0ull;
                k0 |= ((rB & k0) == 0ull) ? (1ull << (i + 1)) : 0ull;
                k0 |= ((rC & k0) == 0ull) ? (1ull << (i + 2)) : 0ull;
                k0 |= ((rD & k0) == 0ull) ? (1ull << (i + 3)) : 0ull;
            }
            for (; i < V; ++i) {
                float4 bA = sbox[i];
                float2 mA = smeta[i];
                bool hA;
                ROW_HIT_LDS(bA, mA, hA);
                unsigned long long rA = __ballot(hA);
                k0 |= ((rA & k0) == 0ull) ? (1ull << i) : 0ull;
            }
        } else {
            nms_slow(sbox, smeta, V, lane, mb, mm, mlab, k0, k1);
        }
#undef ROW_HIT_LDS

        // ---- keep: active -> NMS bit at rank; passive valid -> always kept ----
        float kv0 = 0.0f, kv1 = 0.0f;
        if (vld0) kv0 = act0 ? (float)((((rk0 < 64) ? k0 : k1) >> (rk0 & 63)) & 1ull) : 1.0f;
        if (vld1) kv1 = act1 ? (float)((((rk1 < 64) ? k0 : k1) >> (rk1 & 63)) & 1ull) : 1.0f;
        if (lane < NCELL)
            ((float2*)(out_keep + (size_t)b * NBOX))[lane] = make_float2(kv0, kv1);

        // ---- rotate pipeline registers (unrolled: pure renaming) ----
        if (it + 1 < NB) {
            #pragma unroll
            for (int k = 0; k < 15; ++k) cur[k] = nxt[k];
        }
    }
}

extern "C" void kernel_launch(void* const* d_in, const int* in_sizes, int n_in,
                              void* d_out, int out_size, void* d_ws, size_t ws_size,
                              hipStream_t stream) {
    const float* p = (const float*)d_in[0];
    float* out = (float*)d_out;
    float* out_boxes  = out;
    float* out_scores = out + (size_t)BATCH * NBOX * 4;
    float* out_labels = out_scores + (size_t)BATCH * NBOX;
    float* out_keep   = out_labels + (size_t)BATCH * NBOX;

    yolo_nms_kernel<<<BATCH / (2 * NB), 128, 0, stream>>>(p, out_boxes, out_scores,
                                                          out_labels, out_keep);
}

// Round 6
// 92.465 us; speedup vs baseline: 1.0346x; 1.0346x over previous
//
#include <hip/hip_runtime.h>
#include <math.h>

#define G      7
#define NCELL  49
#define NBOX   98
#define CH     30
#define RAWF   1470
#define BATCH  8192
#define WPB    4      // independent waves (batches) per block

// Wave-internal LDS visibility: drain this wave's outstanding DS ops.
#define WAVE_SYNC() asm volatile("s_waitcnt lgkmcnt(0)" ::: "memory")

__device__ __forceinline__ float sigmoidf_(float x) {
    return 1.0f / (1.0f + expf(-x));
}
// Broadcast lane i's value to all lanes (i wave-uniform SGPR). Pure VALU.
__device__ __forceinline__ float rdlanef(float x, int i) {
    return __int_as_float(__builtin_amdgcn_readlane(__float_as_int(x), i));
}
// Correctly-rounded x/7 (Markstein 2-fma refinement == IEEE x/7.0f here).
__device__ __forceinline__ float div7(float x) {
    const float r7 = 1.0f / 7.0f;
    float q0 = x * r7;
    float e  = fmaf(-7.0f, q0, x);
    return fmaf(e, r7, q0);
}

// Fallback (unreachable with active-filtering; kept for safety) V in (64,98].
__device__ __forceinline__ void nms_slow(const float4* sbox, const float2* smeta,
                                         int V, int lane, float4 mb, float2 mm,
                                         float mlab, unsigned long long& k0,
                                         unsigned long long& k1) {
    const double UD = (double)0.3f + 0x1p-26;
    const int i2c = (lane + 64 < NBOX) ? lane + 64 : NBOX - 1;
    const float4 mb2 = sbox[i2c];
    const float2 mm2 = smeta[i2c];
    const float mlab2 = (lane + 64 < V) ? mm2.y : -1.0f;
    for (int i = 0; i < V; ++i) {
        float bx, by, bz, bw, ba, bl;
        if (i < 64) {
            bx = rdlanef(mb.x, i);  by = rdlanef(mb.y, i);
            bz = rdlanef(mb.z, i);  bw = rdlanef(mb.w, i);
            ba = rdlanef(mm.x, i);  bl = rdlanef(mlab, i);
        } else {
            bx = rdlanef(mb2.x, i - 64);  by = rdlanef(mb2.y, i - 64);
            bz = rdlanef(mb2.z, i - 64);  bw = rdlanef(mb2.w, i - 64);
            ba = rdlanef(mm2.x, i - 64);  bl = rdlanef(mlab2, i - 64);
        }
        float w1 = fmaxf(fminf(bz, mb.z) - fmaxf(bx, mb.x), 0.0f);
        float h1 = fmaxf(fminf(bw, mb.w) - fmaxf(by, mb.y), 0.0f);
        float i1 = w1 * h1;
        float u1 = fmaxf(ba + mm.x - i1, 1e-9f);
        bool hit1 = ((double)i1 > UD * (double)u1) && (bl == mlab);
        float w2 = fmaxf(fminf(bz, mb2.z) - fmaxf(bx, mb2.x), 0.0f);
        float h2 = fmaxf(fminf(bw, mb2.w) - fmaxf(by, mb2.y), 0.0f);
        float i2 = w2 * h2;
        float u2 = fmaxf(ba + mm2.x - i2, 1e-9f);
        bool hit2 = ((double)i2 > UD * (double)u2) && (bl == mlab2);
        unsigned long long row0 = __ballot(hit1);
        unsigned long long row1 = __ballot(hit2);
        if (((row0 & k0) | (row1 & k1)) == 0ull) {
            if (i < 64) k0 |= 1ull << i;
            else        k1 |= 1ull << (i - 64);
        }
    }
}

__global__ __launch_bounds__(64 * WPB, 8) void yolo_nms_kernel(
    const float* __restrict__ p,
    float* __restrict__ out_boxes,   // [B,98,4]
    float* __restrict__ out_scores,  // [B,98]
    float* __restrict__ out_labels,  // [B,98]
    float* __restrict__ out_keep)    // [B,98]
{
#pragma clang fp contract(off)
    // Per-wave LDS; waves are fully independent (no __syncthreads anywhere).
    __shared__ __align__(16) float4 sboxS[WPB][NBOX];   // 1568 B/wave
    __shared__ __align__(8)  float2 smetaS[WPB][NBOX];  //  784 B/wave

    const int lane = threadIdx.x & 63;
    const int wv   = threadIdx.x >> 6;
    const int b    = blockIdx.x * WPB + wv;

    float4* sbox  = sboxS[wv];
    float2* smeta = smetaS[wv];

    const float* base = p + (size_t)b * RAWF;

    // ---- lane-per-cell decode: lane L < 49 owns cell L = boxes {2L, 2L+1}.
    // One row base serves box/conf/class loads; argmax consumed in-lane.
    float4 bb0 = make_float4(0.f, 0.f, 0.f, 0.f);
    float4 bb1 = make_float4(0.f, 0.f, 0.f, 0.f);
    float s0 = -1.0f, s1 = -1.0f, area0 = 0.0f, area1 = 0.0f, lab = 0.0f;
    bool vld0 = false, vld1 = false, act0 = false, act1 = false;

    if (lane < NCELL) {
        const float2* q2 = (const float2*)(base + lane * CH);  // 8B aligned
        float2 xy0 = q2[0];   // tx0, ty0
        float2 wh0 = q2[1];   // tw0, th0
        float2 xy1 = q2[2];   // tx1, ty1
        float2 wh1 = q2[3];   // tw1, th1
        float2 cf  = q2[4];   // conf0, conf1
        // class argmax, two independent chains (x-side even idx, y-side odd),
        // first-max merge == jnp.argmax semantics.
        float2 c0 = q2[5];
        float bx = c0.x; int ix = 0;
        float by = c0.y; int iy = 1;
        #pragma unroll
        for (int k2 = 1; k2 < 10; ++k2) {
            float2 cv = q2[5 + k2];
            if (cv.x > bx) { bx = cv.x; ix = 2 * k2; }
            if (cv.y > by) { by = cv.y; iy = 2 * k2 + 1; }
        }
        const int bi = (by > bx) ? iy : ix;   // tie: iy>ix always, keep ix (first)
        lab = (float)(bi + 1);

        const int r = lane / G, c = lane - r * G;
        float gx0 = div7(sigmoidf_(xy0.x) + (float)c);
        float gy0 = div7(sigmoidf_(xy0.y) + (float)r);
        float gx1 = div7(sigmoidf_(xy1.x) + (float)c);
        float gy1 = div7(sigmoidf_(xy1.y) + (float)r);
        float hx0 = wh0.x * 0.5f, hy0 = wh0.y * 0.5f;
        float hx1 = wh1.x * 0.5f, hy1 = wh1.y * 0.5f;
        bb0 = make_float4(gx0 - hx0, gy0 - hy0, gx0 + hx0, gy0 + hy0);
        bb1 = make_float4(gx1 - hx1, gy1 - hy1, gx1 + hx1, gy1 + hy1);
        area0 = fmaxf(bb0.z - bb0.x, 0.0f) * fmaxf(bb0.w - bb0.y, 0.0f);
        area1 = fmaxf(bb1.z - bb1.x, 0.0f) * fmaxf(bb1.w - bb1.y, 0.0f);
        s0 = sigmoidf_(cf.x);
        s1 = sigmoidf_(cf.y);
        vld0 = (s0 > 0.5f);
        vld1 = (s1 > 0.5f);
        // Zero-area boxes are provably inert under reference NMS (inter==0
        // bitwise for every partner): keep = valid, never suppress. Only
        // active boxes enter sort + NMS.
        act0 = vld0 && (area0 > 0.0f);
        act1 = vld1 && (area1 > 0.0f);

        float4* ob = (float4*)(out_boxes + (size_t)b * (NBOX * 4));
        ob[2 * lane]     = bb0;
        ob[2 * lane + 1] = bb1;
        ((float2*)(out_scores + (size_t)b * NBOX))[lane] = make_float2(s0, s1);
        ((float2*)(out_labels + (size_t)b * NBOX))[lane] = make_float2(lab, lab);
    }

    // ---- active masks (bits confined to lanes 0..48) ----
    unsigned long long m0 = __ballot(act0);   // even boxes 2L
    unsigned long long m1 = __ballot(act1);   // odd boxes 2L+1
    const int V = __popcll(m0) + __popcll(m1);   // E[V] ~ 12

    // ---- stable descending rank via ballot-mask walk + readlane (no LDS).
    // rank = #{active j : s_j > s_me or (s_j == s_me and orig_j < orig_me)}.
    // orig index: even box 2jl, odd 2jl+1 -> tie-breaks are lane compares.
    int rk0 = 0, rk1 = 0;
    unsigned long long t0 = m0;
    while (t0) {
        int jl = __builtin_ctzll(t0); t0 &= t0 - 1ull;
        float sj = rdlanef(s0, jl);
        rk0 += (sj > s0) || ((sj == s0) && (jl <  lane));   // 2jl < 2L
        rk1 += (sj > s1) || ((sj == s1) && (jl <= lane));   // 2jl < 2L+1
    }
    unsigned long long t1 = m1;
    while (t1) {
        int jl = __builtin_ctzll(t1); t1 &= t1 - 1ull;
        float sj = rdlanef(s1, jl);
        rk0 += (sj > s0) || ((sj == s0) && (jl < lane));    // 2jl+1 < 2L
        rk1 += (sj > s1) || ((sj == s1) && (jl < lane));    // 2jl+1 < 2L+1
    }

    // ---- push active boxes to rank-sorted slots; lane <- rank ----
    if (act0) { sbox[rk0] = bb0; smeta[rk0] = make_float2(area0, lab); }
    if (act1) { sbox[rk1] = bb1; smeta[rk1] = make_float2(area1, lab); }
    WAVE_SYNC();
    const float4 mb = sbox[lane];
    const float2 mm = smeta[lane];
    const float mlab = (lane < V) ? mm.y : -1.0f;   // sentinel kills garbage hits

    // ---- fused NMS over active boxes (~12 rows): LDS-broadcast rows,
    //      4-row unroll, ballot + SALU greedy ----
    unsigned long long k0 = 0ull, k1 = 0ull;
    // exact division-free predicate: RN(inter/uc) > 0.3f <=> inter > (0.3f+2^-26)*uc (exact f64)
    const double UD = (double)0.3f + 0x1p-26;

#define ROW_HIT_LDS(BI, MI, HIT) do {                                    \
        float w = fmaxf(fminf((BI).z, mb.z) - fmaxf((BI).x, mb.x), 0.0f);\
        float h = fmaxf(fminf((BI).w, mb.w) - fmaxf((BI).y, mb.y), 0.0f);\
        float inter = w * h;                                             \
        float uc = fmaxf((MI).x + mm.x - inter, 1e-9f);                  \
        HIT = ((double)inter > UD * (double)uc) && ((MI).y == mlab);     \
    } while (0)

    if (V <= 64) {
        int i = 0;
        for (; i + 4 <= V; i += 4) {     // 4 independent row chains in flight
            float4 bA = sbox[i],     bB = sbox[i + 1];
            float4 bC = sbox[i + 2], bD = sbox[i + 3];
            float2 mA = smeta[i],     mB = smeta[i + 1];
            float2 mC = smeta[i + 2], mD = smeta[i + 3];
            bool hA, hB, hC, hD;
            ROW_HIT_LDS(bA, mA, hA);
            ROW_HIT_LDS(bB, mB, hB);
            ROW_HIT_LDS(bC, mC, hC);
            ROW_HIT_LDS(bD, mD, hD);
            unsigned long long rA = __ballot(hA);
            unsigned long long rB = __ballot(hB);
            unsigned long long rC = __ballot(hC);
            unsigned long long rD = __ballot(hD);
            k0 |= ((rA & k0) == 0ull) ? (1ull << i) : 0ull;
            k0 |= ((rB & k0) == 0ull) ? (1ull << (i + 1)) : 0ull;
            k0 |= ((rC & k0) == 0ull) ? (1ull << (i + 2)) : 0ull;
            k0 |= ((rD & k0) == 0ull) ? (1ull << (i + 3)) : 0ull;
        }
        for (; i < V; ++i) {
            float4 bA = sbox[i];
            float2 mA = smeta[i];
            bool hA;
            ROW_HIT_LDS(bA, mA, hA);
            unsigned long long rA = __ballot(hA);
            k0 |= ((rA & k0) == 0ull) ? (1ull << i) : 0ull;
        }
    } else {
        nms_slow(sbox, smeta, V, lane, mb, mm, mlab, k0, k1);
    }
#undef ROW_HIT_LDS

    // ---- keep: active -> NMS bit at own rank; passive valid -> always kept ----
    float kv0 = 0.0f, kv1 = 0.0f;
    if (vld0) kv0 = act0 ? (float)((((rk0 < 64) ? k0 : k1) >> (rk0 & 63)) & 1ull) : 1.0f;
    if (vld1) kv1 = act1 ? (float)((((rk1 < 64) ? k0 : k1) >> (rk1 & 63)) & 1ull) : 1.0f;
    if (lane < NCELL)
        ((float2*)(out_keep + (size_t)b * NBOX))[lane] = make_float2(kv0, kv1);
}

extern "C" void kernel_launch(void* const* d_in, const int* in_sizes, int n_in,
                              void* d_out, int out_size, void* d_ws, size_t ws_size,
                              hipStream_t stream) {
    const float* p = (const float*)d_in[0];
    float* out = (float*)d_out;
    float* out_boxes  = out;
    float* out_scores = out + (size_t)BATCH * NBOX * 4;
    float* out_labels = out_scores + (size_t)BATCH * NBOX;
    float* out_keep   = out_labels + (size_t)BATCH * NBOX;

    yolo_nms_kernel<<<BATCH / WPB, 64 * WPB, 0, stream>>>(p, out_boxes, out_scores,
                                                          out_labels, out_keep);
}